// Round 20
// baseline (71.009 us; speedup 1.0000x reference)
//
#include <hip/hip_runtime.h>
#include <hip/hip_bf16.h>
#include <math.h>
#include <type_traits>

#define B_SZ 2
#define L_SZ 8192
#define DIM 256
#define H_N 8
#define HD 32
#define RAD 32
#define M_ROWS (B_SZ * L_SZ)   // 16384

typedef __bf16 bf16x8 __attribute__((ext_vector_type(8)));
typedef __bf16 bf16x4 __attribute__((ext_vector_type(4)));
typedef short  s16x4  __attribute__((ext_vector_type(4)));
typedef float  f32x4  __attribute__((ext_vector_type(4)));

typedef const __attribute__((address_space(1))) void gvoid_t;
typedef __attribute__((address_space(3))) void lvoid_t;

// XCD-aware block swizzle (bijective when gridDim.x % 8 == 0): blocks resident
// on one XCD (bid%8) get consecutive tile ids -> L2 locality (A panels are
// shared by consecutive tile ids -> same-XCD L2 hits).
static __device__ __forceinline__ int xcd_swz(int id, int nwg) {
    return (id & 7) * (nwg >> 3) + (id >> 3);
}

// 16x16x16 bf16 MFMA with builtin-name portability (A/B: 4 bf16, k = (lane>>4)*4+j)
static __device__ __forceinline__ f32x4 mfma16_bf16(bf16x4 a, bf16x4 b, f32x4 c) {
#if __has_builtin(__builtin_amdgcn_mfma_f32_16x16x16bf16_1k)
    return __builtin_amdgcn_mfma_f32_16x16x16bf16_1k(
        __builtin_bit_cast(s16x4, a), __builtin_bit_cast(s16x4, b), c, 0, 0, 0);
#elif __has_builtin(__builtin_amdgcn_mfma_f32_16x16x16_bf16)
    return __builtin_amdgcn_mfma_f32_16x16x16_bf16(a, b, c, 0, 0, 0);
#else
    f32x4 d = c;
    asm volatile("v_mfma_f32_16x16x16_bf16 %0, %1, %2, %0\n\ts_nop 7\n\ts_nop 7"
                 : "+v"(d) : "v"(a), "v"(b));
    return d;
#endif
}

// ---------------- prep: weight transposes only (x handled inside gemm1) ----
__global__ __launch_bounds__(256) void prep(const float* __restrict__ wq,
                                            const float* __restrict__ wp,
                                            __bf16* __restrict__ wqT,
                                            __bf16* __restrict__ wpT) {
    int idx = blockIdx.x * 256 + threadIdx.x;
    const int N2 = 3 * DIM * DIM;           // 196,608
    if (idx < N2) {
        int n = idx >> 8, k = idx & 255;
        wqT[idx] = (__bf16)wq[(size_t)k * (3 * DIM) + n];
    } else {
        int i3 = idx - N2;                  // < 65,536
        int n = i3 >> 8, k = i3 & 255;
        wpT[i3] = (__bf16)wp[(size_t)k * DIM + n];
    }
}

// ---------------- bf16 MFMA GEMM, 2-phase, A streamed from global ----------
// C[M][N] = A[M][K] * BT[N][K]^T + bias. 1-D grid with XCD swizzle.
// B double-buffered in LDS via global_load_lds; A fragments read DIRECTLY
// from global into registers (per-lane 128-B-segmented, L2-resident via the
// XCD swizzle), double-buffered across K-steps. CAST_A: A is f32; cvt to
// bf16 at compute-top (loads are one iteration old -> no stall).
template<int BM, int BN, int WM, int WN, int N_DIM, int K_DIM, bool OUT_BF16, bool CAST_A>
__global__ __launch_bounds__(256) void gemm_bt(const void* __restrict__ Aptr,
                                               const __bf16* __restrict__ BT,
                                               const float* __restrict__ bias,
                                               void* __restrict__ Cout) {
    constexpr int BK = 32;
    constexpr int FM = BM / WM / 16;
    constexpr int FN = BN / WN / 16;
    constexpr int NT = K_DIM / BK;
    static_assert((NT & 1) == 0, "NT must be even");
    constexpr int NBX = N_DIM / BN;
    __shared__ __bf16 Bs[2][BN * BK];
    const int tid = threadIdx.x;
    const int lane = tid & 63;
    const int wave = tid >> 6;
    const int wr = wave / WN;
    const int wc = wave % WN;
    const int t0 = xcd_swz(blockIdx.x, gridDim.x);
    const int row0 = (t0 / NBX) * BM;
    const int col0 = (t0 % NBX) * BN;

    f32x4 acc[FM][FN] = {};

    const int fr = lane & 15;
    const int fg = lane >> 4;

    auto stage_b = [&](int buf, int k0) {
        #pragma unroll
        for (int i = 0; i < BN / 64; ++i) {
            int c  = tid + i * 256;
            int r  = c >> 2;
            int kk = (c & 3) * 8;
            __builtin_amdgcn_global_load_lds(
                (gvoid_t*)(BT + (size_t)(col0 + r) * K_DIM + (k0 + kk)),
                (lvoid_t*)(&Bs[buf][c * 8]), 16, 0, 0);
        }
    };

    // A fragment loads: global -> regs (raw; cvt deferred to compute)
    auto load_a = [&](int k0, f32x4 (&lo)[FM], f32x4 (&hi)[FM], bf16x8 (&av)[FM]) {
        #pragma unroll
        for (int i = 0; i < FM; ++i) {
            size_t off = (size_t)(row0 + wr * (BM / WM) + i * 16 + fr) * K_DIM + k0 + fg * 8;
            if (CAST_A) {
                const float* ap = (const float*)Aptr + off;
                lo[i] = *reinterpret_cast<const f32x4*>(ap);
                hi[i] = *reinterpret_cast<const f32x4*>(ap + 4);
            } else {
                av[i] = *reinterpret_cast<const bf16x8*>((const __bf16*)Aptr + off);
            }
        }
    };
    auto compute = [&](int buf, f32x4 (&lo)[FM], f32x4 (&hi)[FM], bf16x8 (&av)[FM]) {
        bf16x8 a[FM], b[FN];
        #pragma unroll
        for (int i = 0; i < FM; ++i) {
            if (CAST_A) {
                bf16x8 w;
                #pragma unroll
                for (int j = 0; j < 4; ++j) { w[j] = (__bf16)lo[i][j]; w[j + 4] = (__bf16)hi[i][j]; }
                a[i] = w;
            } else {
                a[i] = av[i];
            }
        }
        #pragma unroll
        for (int j = 0; j < FN; ++j)
            b[j] = *reinterpret_cast<const bf16x8*>(&Bs[buf][(wc * (BN / WN) + j * 16 + fr) * BK + fg * 8]);
        #pragma unroll
        for (int i = 0; i < FM; ++i)
            #pragma unroll
            for (int j = 0; j < FN; ++j)
                acc[i][j] = __builtin_amdgcn_mfma_f32_16x16x32_bf16(a[i], b[j], acc[i][j], 0, 0, 0);
    };

    f32x4 lo0[FM], hi0[FM], lo1[FM], hi1[FM];
    bf16x8 av0[FM], av1[FM];

    stage_b(0, 0);
    load_a(0, lo0, hi0, av0);
    asm volatile("s_waitcnt vmcnt(0)" ::: "memory");
    __syncthreads();
    for (int t = 0; t < NT; t += 2) {
        // prefetch tile t+1 (B->LDS, A->regs), compute tile t
        stage_b(1, (t + 1) * BK);
        load_a((t + 1) * BK, lo1, hi1, av1);
        compute(0, lo0, hi0, av0);
        asm volatile("s_waitcnt vmcnt(0)" ::: "memory");
        __syncthreads();
        if (t + 2 < NT) {
            stage_b(0, (t + 2) * BK);
            load_a((t + 2) * BK, lo0, hi0, av0);
            compute(1, lo1, hi1, av1);
            asm volatile("s_waitcnt vmcnt(0)" ::: "memory");
            __syncthreads();
        } else {
            compute(1, lo1, hi1, av1);   // last tile: no trailing barrier
        }
    }

    #pragma unroll
    for (int i = 0; i < FM; ++i) {
        #pragma unroll
        for (int j = 0; j < FN; ++j) {
            int cc = col0 + wc * (BN / WN) + j * 16 + fr;
            float bv = bias[cc];
            #pragma unroll
            for (int r = 0; r < 4; ++r) {
                int rr = row0 + wr * (BM / WM) + i * 16 + fg * 4 + r;
                float v = acc[i][j][r] + bv;
                if (OUT_BF16)
                    ((__bf16*)Cout)[(size_t)rr * N_DIM + cc] = (__bf16)v;
                else
                    ((float*)Cout)[(size_t)rr * N_DIM + cc] = v;
            }
        }
    }
}

// ---------------- MFMA neighborhood attention, swapped-QK^T (R18 exact) ----
// 256 threads = 4 waves; wave owns 32 q-rows (2 subtiles of 16); block = 128
// q-rows of one (b,h). Swapped QK^T (mfma(K,Q) = S^T) puts each q-row on one
// lane (q=l15, p=16t+4fg+r): per-lane softmax, PV A-frag = lane's own regs.
// V^T staged swizzled in LDS: elem V^T[d][sp] at col ((sp>>3)^((d>>3)&3))*8+(sp&7).
__global__ __launch_bounds__(256) void natt_mfma(const __bf16* __restrict__ qkv,
                                                 __bf16* __restrict__ attn_out) {
    constexpr int VS = 216;                 // row stride (432 B)
    __shared__ __bf16 vsT[32 * VS];         // 13.5 KB, only LDS buffer

    const int tid  = threadIdx.x;
    const int lane = tid & 63;
    const int wave = tid >> 6;
    const int l15  = lane & 15;
    const int fg   = lane >> 4;
    const int t0 = xcd_swz(blockIdx.x, gridDim.x);
    const int bh = t0 >> 6;                 // 64 l-tiles per (b,h)
    const int b  = bh >> 3;
    const int h  = bh & 7;
    const int bq0 = (t0 & 63) * 128;
    const int wq0 = bq0 + wave * 32;

    const __bf16* base = qkv + (size_t)b * L_SZ * 768 + h * 32;

    // stage V^T (swizzled): sp in [0,192), 768 chunks of 8 bf16
    #pragma unroll
    for (int i = 0; i < 3; ++i) {
        int c  = tid + i * 256;
        int sp = c >> 2;
        int dq = c & 3;
        int kp = bq0 - 32 + sp;
        bf16x8 v = {};
        if (kp >= 0 && kp < L_SZ)
            v = *reinterpret_cast<const bf16x8*>(base + (size_t)kp * 768 + 512 + dq * 8);
        int g = (sp >> 3) ^ dq;
        #pragma unroll
        for (int j = 0; j < 8; ++j)
            vsT[(dq * 8 + j) * VS + g * 8 + (sp & 7)] = v[j];
    }

    // K frags: 6 tiles shared by both subtiles; Q frags: 2. OOB rows -> 0
    // (score 0 participates in softmax = reference zero-pad semantics).
    bf16x8 kf[6];
    #pragma unroll
    for (int t = 0; t < 6; ++t) {
        int kp = wq0 - 32 + t * 16 + l15;
        bf16x8 kv = {};
        if (kp >= 0 && kp < L_SZ)
            kv = *reinterpret_cast<const bf16x8*>(base + (size_t)kp * 768 + 256 + fg * 8);
        kf[t] = kv;
    }
    bf16x8 qf[2];
    #pragma unroll
    for (int s = 0; s < 2; ++s)
        qf[s] = *reinterpret_cast<const bf16x8*>(base + (size_t)(wq0 + s * 16 + l15) * 768 + fg * 8);

    __syncthreads();   // vsT staged

    // exp(x/sqrt(32)) = exp2(x * (log2e/sqrt(32)))
    const float cexp = 0.25501764f;

    #pragma unroll
    for (int s = 0; s < 2; ++s) {
        // swapped QK^T: st[t] lane(fg,l15) reg r = S[q=l15][p=16t+4fg+r]
        f32x4 st[5];
        #pragma unroll
        for (int t = 0; t < 5; ++t)
            st[t] = __builtin_amdgcn_mfma_f32_16x16x32_bf16(kf[s + t], qf[s], f32x4{}, 0, 0, 0);

        // per-lane masked exp + fg-group sum (band: qr <= pr <= qr+64, qr=l15)
        const int qr = l15;
        float sum = 0.f;
        #pragma unroll
        for (int t = 0; t < 5; ++t) {
            #pragma unroll
            for (int r = 0; r < 4; ++r) {
                int pr = 16 * t + 4 * fg + r;
                bool valid = (pr >= qr) && (pr <= qr + 64);
                float e = valid ? exp2f(st[t][r] * cexp) : 0.f;
                st[t][r] = e;
                sum += e;
            }
        }
        sum += __shfl_xor(sum, 16);
        sum += __shfl_xor(sum, 32);
        float inv = 1.f / sum;

        // normalized P fragments: pf[t] = A-frag of 16x16x16 (k = fg*4+j)
        bf16x4 pf[5];
        #pragma unroll
        for (int t = 0; t < 5; ++t) {
            bf16x4 p;
            #pragma unroll
            for (int r = 0; r < 4; ++r) p[r] = (__bf16)(st[t][r] * inv);
            pf[t] = p;
        }

        // PV: O[16q][32d] = P[16x80] * V[80x32] via 5 p-tiles x 2 d-tiles
        f32x4 acc[2] = {};
        #pragma unroll
        for (int c = 0; c < 5; ++c) {
            #pragma unroll
            for (int dt = 0; dt < 2; ++dt) {
                // V^T[d = dt*16+l15][sp = wave*32+s*16+16c+4fg+j], swizzled b64
                int g = (4 * wave + 2 * s + 2 * c + (fg >> 1)) ^ (2 * dt + (l15 >> 3));
                bf16x4 vf = *reinterpret_cast<const bf16x4*>(
                    &vsT[(dt * 16 + l15) * VS + g * 8 + 4 * (fg & 1)]);
                acc[dt] = mfma16_bf16(pf[c], vf, acc[dt]);
            }
        }

        // store (already normalized): row q = fg*4+r, col d = dt*16+l15
        __bf16* outp = attn_out + ((size_t)(b * L_SZ + wq0 + s * 16)) * 256 + h * 32;
        #pragma unroll
        for (int dt = 0; dt < 2; ++dt)
            #pragma unroll
            for (int r = 0; r < 4; ++r)
                outp[(size_t)(fg * 4 + r) * 256 + dt * 16 + l15] = (__bf16)acc[dt][r];
    }
}

extern "C" void kernel_launch(void* const* d_in, const int* in_sizes, int n_in,
                              void* d_out, int out_size, void* d_ws, size_t ws_size,
                              hipStream_t stream) {
    const float* x      = (const float*)d_in[0];
    const float* w_qkv  = (const float*)d_in[1];
    const float* b_qkv  = (const float*)d_in[2];
    const float* w_proj = (const float*)d_in[3];
    const float* b_proj = (const float*)d_in[4];
    float* out = (float*)d_out;

    __bf16* wqkvT  = (__bf16*)d_ws;                               // 768*256
    __bf16* wprojT = wqkvT + (size_t)(3 * DIM) * DIM;             // 256*256
    __bf16* qkvb   = wprojT + (size_t)DIM * DIM;                  // 16384*768
    __bf16* ab     = qkvb  + (size_t)M_ROWS * (3 * DIM);          // 16384*256

    // weight transposes: 262,144 items
    prep<<<1024, 256, 0, stream>>>(w_qkv, w_proj, wqkvT, wprojT);

    // qkv = x @ w_qkv + b_qkv  (x is f32, A streamed from global + cvt)
    gemm_bt<128, 128, 2, 2, 3 * DIM, DIM, true, true>
        <<<(M_ROWS / 128) * (3 * DIM / 128), 256, 0, stream>>>(x, wqkvT, b_qkv, qkvb);

    // neighborhood attention (1024 blocks of 128 q-rows, XCD-swizzled)
    natt_mfma<<<(L_SZ / 128) * (B_SZ * H_N), 256, 0, stream>>>(qkvb, ab);

    // out = ab @ w_proj + b_proj  (A bf16 streamed from global)
    gemm_bt<64, 128, 1, 4, DIM, DIM, false, false>
        <<<(M_ROWS / 64) * (DIM / 128), 256, 0, stream>>>(ab, wprojT, b_proj, out);
}

// Round 21
// 45.095 us; speedup vs baseline: 1.5747x; 1.5747x over previous
//
#include <hip/hip_runtime.h>
#include <hip/hip_bf16.h>
#include <math.h>
#include <type_traits>

#define B_SZ 2
#define L_SZ 8192
#define DIM 256
#define H_N 8
#define HD 32
#define RAD 32
#define M_ROWS (B_SZ * L_SZ)   // 16384

typedef __bf16 bf16x8 __attribute__((ext_vector_type(8)));
typedef __bf16 bf16x4 __attribute__((ext_vector_type(4)));
typedef short  s16x4  __attribute__((ext_vector_type(4)));
typedef float  f32x4  __attribute__((ext_vector_type(4)));

typedef const __attribute__((address_space(1))) void gvoid_t;
typedef __attribute__((address_space(3))) void lvoid_t;

// XCD-aware block swizzle (bijective when gridDim.x % 8 == 0): blocks resident
// on one XCD (bid%8) get consecutive tile ids -> L2 locality.
static __device__ __forceinline__ int xcd_swz(int id, int nwg) {
    return (id & 7) * (nwg >> 3) + (id >> 3);
}

// 16x16x16 bf16 MFMA with builtin-name portability (A/B: 4 bf16, k = (lane>>4)*4+j)
static __device__ __forceinline__ f32x4 mfma16_bf16(bf16x4 a, bf16x4 b, f32x4 c) {
#if __has_builtin(__builtin_amdgcn_mfma_f32_16x16x16bf16_1k)
    return __builtin_amdgcn_mfma_f32_16x16x16bf16_1k(
        __builtin_bit_cast(s16x4, a), __builtin_bit_cast(s16x4, b), c, 0, 0, 0);
#elif __has_builtin(__builtin_amdgcn_mfma_f32_16x16x16_bf16)
    return __builtin_amdgcn_mfma_f32_16x16x16_bf16(a, b, c, 0, 0, 0);
#else
    f32x4 d = c;
    asm volatile("v_mfma_f32_16x16x16_bf16 %0, %1, %2, %0\n\ts_nop 7\n\ts_nop 7"
                 : "+v"(d) : "v"(a), "v"(b));
    return d;
#endif
}

// ---------------- prep: weight transposes only (x handled inside gemm1) ----
__global__ __launch_bounds__(256) void prep(const float* __restrict__ wq,
                                            const float* __restrict__ wp,
                                            __bf16* __restrict__ wqT,
                                            __bf16* __restrict__ wpT) {
    int idx = blockIdx.x * 256 + threadIdx.x;
    const int N2 = 3 * DIM * DIM;           // 196,608
    if (idx < N2) {
        int n = idx >> 8, k = idx & 255;
        wqT[idx] = (__bf16)wq[(size_t)k * (3 * DIM) + n];
    } else {
        int i3 = idx - N2;                  // < 65,536
        int n = i3 >> 8, k = i3 & 255;
        wpT[i3] = (__bf16)wp[(size_t)k * DIM + n];
    }
}

// ---------------- bf16 MFMA GEMM, 2-phase double-buffered (R12 exact) ------
template<int BM, int BN, int WM, int WN, int N_DIM, int K_DIM, bool OUT_BF16, bool CAST_A>
__global__ __launch_bounds__(256) void gemm_bt(const void* __restrict__ Aptr,
                                               const __bf16* __restrict__ BT,
                                               const float* __restrict__ bias,
                                               void* __restrict__ Cout) {
    constexpr int BK = 32;
    constexpr int FM = BM / WM / 16;
    constexpr int FN = BN / WN / 16;
    constexpr int NT = K_DIM / BK;
    constexpr int NBX = N_DIM / BN;
    using AT = typename std::conditional<CAST_A, float, __bf16>::type;
    __shared__ AT As[2][BM * BK];
    __shared__ __bf16 Bs[2][BN * BK];
    const int tid = threadIdx.x;
    const int lane = tid & 63;
    const int wave = tid >> 6;
    const int wr = wave / WN;
    const int wc = wave % WN;
    const int t0 = xcd_swz(blockIdx.x, gridDim.x);
    const int row0 = (t0 / NBX) * BM;
    const int col0 = (t0 % NBX) * BN;

    f32x4 acc[FM][FN] = {};

    const int fr = lane & 15;
    const int fg = lane >> 4;

    auto stage = [&](int buf, int k0) {
        if (CAST_A) {
            const float* Af = (const float*)Aptr;
            #pragma unroll
            for (int i = 0; i < BM * 8 / 256; ++i) {
                int c  = tid + i * 256;
                int r  = c >> 3;
                int kk = (c & 7) * 4;
                __builtin_amdgcn_global_load_lds(
                    (gvoid_t*)(Af + (size_t)(row0 + r) * K_DIM + (k0 + kk)),
                    (lvoid_t*)((float*)As[buf] + c * 4), 16, 0, 0);
            }
        } else {
            const __bf16* Ab = (const __bf16*)Aptr;
            #pragma unroll
            for (int i = 0; i < BM / 64; ++i) {
                int c  = tid + i * 256;
                int r  = c >> 2;
                int kk = (c & 3) * 8;
                __builtin_amdgcn_global_load_lds(
                    (gvoid_t*)(Ab + (size_t)(row0 + r) * K_DIM + (k0 + kk)),
                    (lvoid_t*)((__bf16*)As[buf] + c * 8), 16, 0, 0);
            }
        }
        #pragma unroll
        for (int i = 0; i < BN / 64; ++i) {
            int c  = tid + i * 256;
            int r  = c >> 2;
            int kk = (c & 3) * 8;
            __builtin_amdgcn_global_load_lds(
                (gvoid_t*)(BT + (size_t)(col0 + r) * K_DIM + (k0 + kk)),
                (lvoid_t*)(&Bs[buf][c * 8]), 16, 0, 0);
        }
    };
    auto compute = [&](int buf) {
        bf16x8 a[FM], b[FN];
        #pragma unroll
        for (int i = 0; i < FM; ++i) {
            int rr = wr * (BM / WM) + i * 16 + fr;
            if (CAST_A) {
                const float* ap = (const float*)As[buf] + rr * BK + fg * 8;
                f32x4 lo = *reinterpret_cast<const f32x4*>(ap);
                f32x4 hi = *reinterpret_cast<const f32x4*>(ap + 4);
                bf16x8 w;
                #pragma unroll
                for (int j = 0; j < 4; ++j) { w[j] = (__bf16)lo[j]; w[j + 4] = (__bf16)hi[j]; }
                a[i] = w;
            } else {
                a[i] = *reinterpret_cast<const bf16x8*>((const __bf16*)As[buf] + rr * BK + fg * 8);
            }
        }
        #pragma unroll
        for (int j = 0; j < FN; ++j)
            b[j] = *reinterpret_cast<const bf16x8*>(&Bs[buf][(wc * (BN / WN) + j * 16 + fr) * BK + fg * 8]);
        #pragma unroll
        for (int i = 0; i < FM; ++i)
            #pragma unroll
            for (int j = 0; j < FN; ++j)
                acc[i][j] = __builtin_amdgcn_mfma_f32_16x16x32_bf16(a[i], b[j], acc[i][j], 0, 0, 0);
    };

    stage(0, 0);
    asm volatile("s_waitcnt vmcnt(0)" ::: "memory");
    __syncthreads();
    int cur = 0;
    for (int t = 0; t < NT - 1; ++t) {
        stage(cur ^ 1, (t + 1) * BK);      // prefetch next tile (stays in flight)
        compute(cur);                      // ds_read + MFMA on current tile
        asm volatile("s_waitcnt vmcnt(0)" ::: "memory");
        __syncthreads();
        cur ^= 1;
    }
    compute(cur);                          // epilogue tile (no prefetch)

    #pragma unroll
    for (int i = 0; i < FM; ++i) {
        #pragma unroll
        for (int j = 0; j < FN; ++j) {
            int cc = col0 + wc * (BN / WN) + j * 16 + fr;
            float bv = bias[cc];
            #pragma unroll
            for (int r = 0; r < 4; ++r) {
                int rr = row0 + wr * (BM / WM) + i * 16 + fg * 4 + r;
                float v = acc[i][j][r] + bv;
                if (OUT_BF16)
                    ((__bf16*)Cout)[(size_t)rr * N_DIM + cc] = (__bf16)v;
                else
                    ((float*)Cout)[(size_t)rr * N_DIM + cc] = v;
            }
        }
    }
}

// ---------------- MFMA neighborhood attention, swapped-QK^T (R18 exact) ----
// 256 threads = 4 waves; wave owns 32 q-rows (2 subtiles of 16); block = 128
// q-rows of one (b,h). Swapped QK^T (mfma(K,Q) = S^T) puts each q-row on one
// lane (q=l15, p=16t+4fg+r): per-lane softmax, PV A-frag = lane's own regs.
// V^T staged swizzled in LDS: elem V^T[d][sp] at col ((sp>>3)^((d>>3)&3))*8+(sp&7).
__global__ __launch_bounds__(256) void natt_mfma(const __bf16* __restrict__ qkv,
                                                 __bf16* __restrict__ attn_out) {
    constexpr int VS = 216;                 // row stride (432 B)
    __shared__ __bf16 vsT[32 * VS];         // 13.5 KB, only LDS buffer

    const int tid  = threadIdx.x;
    const int lane = tid & 63;
    const int wave = tid >> 6;
    const int l15  = lane & 15;
    const int fg   = lane >> 4;
    const int t0 = xcd_swz(blockIdx.x, gridDim.x);
    const int bh = t0 >> 6;                 // 64 l-tiles per (b,h)
    const int b  = bh >> 3;
    const int h  = bh & 7;
    const int bq0 = (t0 & 63) * 128;
    const int wq0 = bq0 + wave * 32;

    const __bf16* base = qkv + (size_t)b * L_SZ * 768 + h * 32;

    // stage V^T (swizzled): sp in [0,192), 768 chunks of 8 bf16
    #pragma unroll
    for (int i = 0; i < 3; ++i) {
        int c  = tid + i * 256;
        int sp = c >> 2;
        int dq = c & 3;
        int kp = bq0 - 32 + sp;
        bf16x8 v = {};
        if (kp >= 0 && kp < L_SZ)
            v = *reinterpret_cast<const bf16x8*>(base + (size_t)kp * 768 + 512 + dq * 8);
        int g = (sp >> 3) ^ dq;
        #pragma unroll
        for (int j = 0; j < 8; ++j)
            vsT[(dq * 8 + j) * VS + g * 8 + (sp & 7)] = v[j];
    }

    // K frags: 6 tiles shared by both subtiles; Q frags: 2. OOB rows -> 0
    // (score 0 participates in softmax = reference zero-pad semantics).
    bf16x8 kf[6];
    #pragma unroll
    for (int t = 0; t < 6; ++t) {
        int kp = wq0 - 32 + t * 16 + l15;
        bf16x8 kv = {};
        if (kp >= 0 && kp < L_SZ)
            kv = *reinterpret_cast<const bf16x8*>(base + (size_t)kp * 768 + 256 + fg * 8);
        kf[t] = kv;
    }
    bf16x8 qf[2];
    #pragma unroll
    for (int s = 0; s < 2; ++s)
        qf[s] = *reinterpret_cast<const bf16x8*>(base + (size_t)(wq0 + s * 16 + l15) * 768 + fg * 8);

    __syncthreads();   // vsT staged

    // exp(x/sqrt(32)) = exp2(x * (log2e/sqrt(32)))
    const float cexp = 0.25501764f;

    #pragma unroll
    for (int s = 0; s < 2; ++s) {
        // swapped QK^T: st[t] lane(fg,l15) reg r = S[q=l15][p=16t+4fg+r]
        f32x4 st[5];
        #pragma unroll
        for (int t = 0; t < 5; ++t)
            st[t] = __builtin_amdgcn_mfma_f32_16x16x32_bf16(kf[s + t], qf[s], f32x4{}, 0, 0, 0);

        // per-lane masked exp + fg-group sum (band: qr <= pr <= qr+64, qr=l15)
        const int qr = l15;
        float sum = 0.f;
        #pragma unroll
        for (int t = 0; t < 5; ++t) {
            #pragma unroll
            for (int r = 0; r < 4; ++r) {
                int pr = 16 * t + 4 * fg + r;
                bool valid = (pr >= qr) && (pr <= qr + 64);
                float e = valid ? exp2f(st[t][r] * cexp) : 0.f;
                st[t][r] = e;
                sum += e;
            }
        }
        sum += __shfl_xor(sum, 16);
        sum += __shfl_xor(sum, 32);
        float inv = 1.f / sum;

        // normalized P fragments: pf[t] = A-frag of 16x16x16 (k = fg*4+j)
        bf16x4 pf[5];
        #pragma unroll
        for (int t = 0; t < 5; ++t) {
            bf16x4 p;
            #pragma unroll
            for (int r = 0; r < 4; ++r) p[r] = (__bf16)(st[t][r] * inv);
            pf[t] = p;
        }

        // PV: O[16q][32d] = P[16x80] * V[80x32] via 5 p-tiles x 2 d-tiles
        f32x4 acc[2] = {};
        #pragma unroll
        for (int c = 0; c < 5; ++c) {
            #pragma unroll
            for (int dt = 0; dt < 2; ++dt) {
                // V^T[d = dt*16+l15][sp = wave*32+s*16+16c+4fg+j], swizzled b64
                int g = (4 * wave + 2 * s + 2 * c + (fg >> 1)) ^ (2 * dt + (l15 >> 3));
                bf16x4 vf = *reinterpret_cast<const bf16x4*>(
                    &vsT[(dt * 16 + l15) * VS + g * 8 + 4 * (fg & 1)]);
                acc[dt] = mfma16_bf16(pf[c], vf, acc[dt]);
            }
        }

        // store (already normalized): row q = fg*4+r, col d = dt*16+l15
        __bf16* outp = attn_out + ((size_t)(b * L_SZ + wq0 + s * 16)) * 256 + h * 32;
        #pragma unroll
        for (int dt = 0; dt < 2; ++dt)
            #pragma unroll
            for (int r = 0; r < 4; ++r)
                outp[(size_t)(fg * 4 + r) * 256 + dt * 16 + l15] = (__bf16)acc[dt][r];
    }
}

extern "C" void kernel_launch(void* const* d_in, const int* in_sizes, int n_in,
                              void* d_out, int out_size, void* d_ws, size_t ws_size,
                              hipStream_t stream) {
    const float* x      = (const float*)d_in[0];
    const float* w_qkv  = (const float*)d_in[1];
    const float* b_qkv  = (const float*)d_in[2];
    const float* w_proj = (const float*)d_in[3];
    const float* b_proj = (const float*)d_in[4];
    float* out = (float*)d_out;

    __bf16* wqkvT  = (__bf16*)d_ws;                               // 768*256
    __bf16* wprojT = wqkvT + (size_t)(3 * DIM) * DIM;             // 256*256
    __bf16* qkvb   = wprojT + (size_t)DIM * DIM;                  // 16384*768
    __bf16* ab     = qkvb  + (size_t)M_ROWS * (3 * DIM);          // 16384*256

    // weight transposes: 262,144 items
    prep<<<1024, 256, 0, stream>>>(w_qkv, w_proj, wqkvT, wprojT);

    // qkv = x @ w_qkv + b_qkv  (x is f32, cast fused via f32 LDS staging)
    gemm_bt<128, 128, 2, 2, 3 * DIM, DIM, true, true>
        <<<(M_ROWS / 128) * (3 * DIM / 128), 256, 0, stream>>>(x, wqkvT, b_qkv, qkvb);

    // neighborhood attention (1024 blocks of 128 q-rows, XCD-swizzled)
    natt_mfma<<<(L_SZ / 128) * (B_SZ * H_N), 256, 0, stream>>>(qkvb, ab);

    // out = ab @ w_proj + b_proj
    gemm_bt<64, 128, 1, 4, DIM, DIM, false, false>
        <<<(M_ROWS / 64) * (DIM / 128), 256, 0, stream>>>(ab, wprojT, b_proj, out);
}